// Round 1
// baseline (1097.746 us; speedup 1.0000x reference)
//
#include <hip/hip_runtime.h>
#include <cstdint>
#include <cstddef>

// Problem constants (B=4, V=64, E=1024, L=1024, D=256, DEG=16)
constexpr int Bv = 4;
constexpr int Vv = 64;
constexpr int Ev = 1024;      // edges per batch
constexpr int Lv = 1024;
constexpr int Dv = 256;
constexpr int BE = Bv * Ev;   // 4096
constexpr size_t EI_PLANE = (size_t)BE * Lv;  // 4,194,304 elements per ei plane

constexpr int HS_STRIDE = 260; // padded fp32 row stride (260%4==0 -> 16B aligned float4 rows)

// ---------------------------------------------------------------------------
// Precompute:  Mt[t*256+d] = sum_i Wq[i*256+d] * Wk[i*256+t]   (M^T, row-major by t)
//              rv[t]       = sum_i bq[i]       * Wk[i*256+t]
// (bk and bq-only terms drop out of the softmax -> never needed)
// ---------------------------------------------------------------------------
__global__ __launch_bounds__(256) void precompute_kernel(
    const float* __restrict__ Wq, const float* __restrict__ Wk,
    const float* __restrict__ bq, float* __restrict__ Mt, float* __restrict__ rv)
{
    const int t = threadIdx.x;
    const int x = blockIdx.x;
    if (x < 256) {
        float a0 = 0.f, a1 = 0.f, a2 = 0.f, a3 = 0.f;
        for (int i = 0; i < 256; i += 4) {
            a0 = fmaf(Wq[(i + 0) * 256 + x], Wk[(i + 0) * 256 + t], a0);
            a1 = fmaf(Wq[(i + 1) * 256 + x], Wk[(i + 1) * 256 + t], a1);
            a2 = fmaf(Wq[(i + 2) * 256 + x], Wk[(i + 2) * 256 + t], a2);
            a3 = fmaf(Wq[(i + 3) * 256 + x], Wk[(i + 3) * 256 + t], a3);
        }
        Mt[t * 256 + x] = (a0 + a1) + (a2 + a3);
    } else {
        float a0 = 0.f, a1 = 0.f, a2 = 0.f, a3 = 0.f;
        for (int i = 0; i < 256; i += 4) {
            a0 = fmaf(bq[i + 0], Wk[(i + 0) * 256 + t], a0);
            a1 = fmaf(bq[i + 1], Wk[(i + 1) * 256 + t], a1);
            a2 = fmaf(bq[i + 2], Wk[(i + 2) * 256 + t], a2);
            a3 = fmaf(bq[i + 3], Wk[(i + 3) * 256 + t], a3);
        }
        rv[t] = (a0 + a1) + (a2 + a3);
    }
}

// ---------------------------------------------------------------------------
// Main fused kernel: one block per (b, l).
//  1) stage hs[b, :, l, :] (64 x 256 fp32) into LDS
//  2) T = hs_tile @ M + r   (thread micro-tile: 16 rows x 4 cols)
//  3) per-edge logit = (T[src] . hs[dst]) / 16
//  4) softmax over aligned groups of 16 edges (4 lanes, shfl_xor)
//  5) USE_WS: write probs[bl*1024 + e] coalesced to workspace
//     else:   write ew_out scattered directly (fallback if ws too small)
// ---------------------------------------------------------------------------
template <bool USE_WS>
__global__ __launch_bounds__(256) void edge_main(
    const float* __restrict__ hs, const int* __restrict__ eidx,
    const float* __restrict__ ew, const float* __restrict__ skipp,
    const float* __restrict__ Mt, const float* __restrict__ rv,
    float* __restrict__ probs_or_out)
{
    __shared__ float hs_s[64 * HS_STRIDE];
    __shared__ float T_s[64 * HS_STRIDE];

    const int bl = blockIdx.x;          // 0..4095
    const int b  = bl >> 10;
    const int l  = bl & 1023;
    const int tid = threadIdx.x;

    // ---- stage hs tile (64 rows x 256 cols), float4 loads, coalesced ----
    {
        const float* base = hs + ((size_t)b * 64 * 1024 + (size_t)l) * 256;
        const int c4 = (tid & 63) * 4;      // column (float4)
        const int vo = tid >> 6;            // 0..3
        #pragma unroll
        for (int k = 0; k < 16; ++k) {
            const int v = k * 4 + vo;
            float4 val = *(const float4*)(base + (size_t)v * (1024 * 256) + c4);
            *(float4*)(&hs_s[v * HS_STRIDE + c4]) = val;
        }
    }
    __syncthreads();

    // ---- T-GEMM: thread (vr, tq) computes T[vr*16+i][tq + 64*j] ----
    const int vr = tid >> 6;   // 0..3
    const int tq = tid & 63;   // 0..63
    float acc[16][4];
    #pragma unroll
    for (int j = 0; j < 4; ++j) {
        const float rj = rv[tq + 64 * j];   // fold r bias into T (softmax-relevant part)
        #pragma unroll
        for (int i = 0; i < 16; ++i) acc[i][j] = rj;
    }

    for (int d = 0; d < 256; d += 4) {
        const float4 m0 = *(const float4*)(Mt + (tq +   0) * 256 + d);
        const float4 m1 = *(const float4*)(Mt + (tq +  64) * 256 + d);
        const float4 m2 = *(const float4*)(Mt + (tq + 128) * 256 + d);
        const float4 m3 = *(const float4*)(Mt + (tq + 192) * 256 + d);
        #pragma unroll
        for (int i = 0; i < 16; ++i) {
            const float4 h = *(const float4*)(&hs_s[(vr * 16 + i) * HS_STRIDE + d]);
            acc[i][0] = fmaf(h.w, m0.w, fmaf(h.z, m0.z, fmaf(h.y, m0.y, fmaf(h.x, m0.x, acc[i][0]))));
            acc[i][1] = fmaf(h.w, m1.w, fmaf(h.z, m1.z, fmaf(h.y, m1.y, fmaf(h.x, m1.x, acc[i][1]))));
            acc[i][2] = fmaf(h.w, m2.w, fmaf(h.z, m2.z, fmaf(h.y, m2.y, fmaf(h.x, m2.x, acc[i][2]))));
            acc[i][3] = fmaf(h.w, m3.w, fmaf(h.z, m3.z, fmaf(h.y, m3.y, fmaf(h.x, m3.x, acc[i][3]))));
        }
    }

    // store T to LDS (no barrier needed before: distinct buffer from hs_s)
    #pragma unroll
    for (int i = 0; i < 16; ++i) {
        #pragma unroll
        for (int j = 0; j < 4; ++j)
            T_s[(vr * 16 + i) * HS_STRIDE + tq + 64 * j] = acc[i][j];
    }
    __syncthreads();

    // ---- per-edge logits: thread handles 4 consecutive edges ----
    const int e0  = tid * 4;
    const int be0 = b * Ev + e0;
    int srcs[4], dsts[4];
    #pragma unroll
    for (int j = 0; j < 4; ++j) {
        srcs[j] = eidx[be0 + j];
        dsts[j] = eidx[BE + be0 + j];
    }

    float lg[4];
    #pragma unroll
    for (int j = 0; j < 4; ++j) {
        const float* Tr = &T_s[srcs[j] * HS_STRIDE];
        const float* Hr = &hs_s[dsts[j] * HS_STRIDE];
        float s0 = 0.f, s1 = 0.f, s2 = 0.f, s3 = 0.f;
        for (int d = 0; d < 256; d += 4) {
            const float4 tv = *(const float4*)(Tr + d);
            const float4 hv = *(const float4*)(Hr + d);
            s0 = fmaf(tv.x, hv.x, s0);
            s1 = fmaf(tv.y, hv.y, s1);
            s2 = fmaf(tv.z, hv.z, s2);
            s3 = fmaf(tv.w, hv.w, s3);
        }
        lg[j] = ((s0 + s1) + (s2 + s3)) * 0.0625f;  // 1/sqrt(256)
    }

    // ---- softmax over group of 16 edges = this lane's 4 + 3 neighbor lanes ----
    float mx = fmaxf(fmaxf(lg[0], lg[1]), fmaxf(lg[2], lg[3]));
    mx = fmaxf(mx, __shfl_xor(mx, 1));
    mx = fmaxf(mx, __shfl_xor(mx, 2));
    float ex[4], sm = 0.f;
    #pragma unroll
    for (int j = 0; j < 4; ++j) { ex[j] = __expf(lg[j] - mx); sm += ex[j]; }
    sm += __shfl_xor(sm, 1);
    sm += __shfl_xor(sm, 2);
    const float inv = 1.0f / sm;

    if (USE_WS) {
        float4 o = make_float4(ex[0] * inv, ex[1] * inv, ex[2] * inv, ex[3] * inv);
        *(float4*)(probs_or_out + (size_t)bl * 1024 + e0) = o;
    } else {
        const float skip = skipp[0];
        const float om = 1.0f - skip;
        #pragma unroll
        for (int j = 0; j < 4; ++j) {
            float g = fmaf(skip, ew[be0 + j], om * (ex[j] * inv));
            probs_or_out[(size_t)(be0 + j) * Lv + l] = g;
        }
    }
}

// ---------------------------------------------------------------------------
// Output kernel: tiled transpose of probs (b,l,e) -> ew_out (be,l), plus ei
// broadcast. Block = (lt, et, b) transposes one 64x64 tile.
// ---------------------------------------------------------------------------
__global__ __launch_bounds__(256) void output_kernel(
    const float* __restrict__ probs, const int* __restrict__ eidx,
    const float* __restrict__ ew, const float* __restrict__ skipp,
    float* __restrict__ out)
{
    __shared__ float tile[64 * 68];
    const int lt = blockIdx.x;   // 0..15
    const int et = blockIdx.y;   // 0..15
    const int b  = blockIdx.z;   // 0..3
    const int t  = threadIdx.x;
    const int tr = t >> 4;       // 0..15
    const int tc = t & 15;       // 0..15

    #pragma unroll
    for (int q = 0; q < 4; ++q) {
        const int lloc = q * 16 + tr;
        float4 v = *(const float4*)(probs +
            ((size_t)(b * 1024 + lt * 64 + lloc)) * 1024 + et * 64 + tc * 4);
        *(float4*)(&tile[lloc * 68 + tc * 4]) = v;
    }
    __syncthreads();

    const float skip = skipp[0];
    const float om = 1.0f - skip;
    float* out_ei0 = out;
    float* out_ei1 = out + EI_PLANE;
    float* out_ew  = out + 2 * EI_PLANE;

    #pragma unroll
    for (int q = 0; q < 4; ++q) {
        const int eloc = q * 16 + tr;
        const int be = b * Ev + et * 64 + eloc;
        const float w  = ew[be];
        const float sv = (float)eidx[be];
        const float dv = (float)eidx[BE + be];
        const int lloc0 = tc * 4;
        float4 o;
        o.x = fmaf(skip, w, om * tile[(lloc0 + 0) * 68 + eloc]);
        o.y = fmaf(skip, w, om * tile[(lloc0 + 1) * 68 + eloc]);
        o.z = fmaf(skip, w, om * tile[(lloc0 + 2) * 68 + eloc]);
        o.w = fmaf(skip, w, om * tile[(lloc0 + 3) * 68 + eloc]);
        const size_t off = (size_t)be * Lv + lt * 64 + lloc0;
        *(float4*)(out_ew  + off) = o;
        *(float4*)(out_ei0 + off) = make_float4(sv, sv, sv, sv);
        *(float4*)(out_ei1 + off) = make_float4(dv, dv, dv, dv);
    }
}

// Fallback ei broadcast kernel (only used if ws too small for probs buffer)
__global__ __launch_bounds__(256) void ei_kernel(
    const int* __restrict__ eidx, float* __restrict__ out)
{
    const int blk = blockIdx.x;            // 0..8191  (c*4096 + j)
    const int c = blk >> 12;
    const int j = blk & 4095;
    const float v = (float)eidx[c * BE + j];
    float4 o = make_float4(v, v, v, v);
    *(float4*)(out + (size_t)blk * 1024 + threadIdx.x * 4) = o;
}

// ---------------------------------------------------------------------------
extern "C" void kernel_launch(void* const* d_in, const int* in_sizes, int n_in,
                              void* d_out, int out_size, void* d_ws, size_t ws_size,
                              hipStream_t stream)
{
    const float* hs   = (const float*)d_in[0];
    const int*   eidx = (const int*)d_in[1];
    const float* ew   = (const float*)d_in[2];
    const float* Wq   = (const float*)d_in[3];
    const float* bq   = (const float*)d_in[4];
    const float* Wk   = (const float*)d_in[5];
    // d_in[6] = bk: provably unused (cancels in softmax)
    const float* skip = (const float*)d_in[7];

    float* Mt    = (float*)d_ws;           // 65536 floats (M^T)
    float* rv    = Mt + 65536;             // 256 floats
    float* probs = rv + 256;               // 4M floats
    const size_t need = (size_t)(65536 + 256 + (size_t)Bv * Lv * Ev) * sizeof(float);

    precompute_kernel<<<dim3(257), dim3(256), 0, stream>>>(Wq, Wk, bq, Mt, rv);

    if (ws_size >= need) {
        edge_main<true><<<dim3(Bv * Lv), dim3(256), 0, stream>>>(
            hs, eidx, ew, skip, Mt, rv, probs);
        output_kernel<<<dim3(16, 16, 4), dim3(256), 0, stream>>>(
            probs, eidx, ew, skip, (float*)d_out);
    } else {
        float* out_ew = (float*)d_out + 2 * EI_PLANE;
        edge_main<false><<<dim3(Bv * Lv), dim3(256), 0, stream>>>(
            hs, eidx, ew, skip, Mt, rv, out_ew);
        ei_kernel<<<dim3(2 * BE), dim3(256), 0, stream>>>(eidx, (float*)d_out);
    }
}

// Round 2
// 448.525 us; speedup vs baseline: 2.4475x; 2.4475x over previous
//
#include <hip/hip_runtime.h>
#include <cstdint>
#include <cstddef>

// Problem constants (B=4, V=64, E=1024, L=1024, D=256, DEG=16)
constexpr int Bv = 4;
constexpr int Vv = 64;
constexpr int Ev = 1024;      // edges per batch
constexpr int Lv = 1024;
constexpr int BE = Bv * Ev;   // 4096
constexpr size_t EI_PLANE = (size_t)BE * Lv;  // 4,194,304 elements per ei plane

// bf16 LDS row stride: 256 + 8 pad -> 528 B rows (16B aligned, fragment b128
// reads land 2-way on banks which is free; power-of-2 512 B would be 16-way)
constexpr int STRB = 264;

typedef __bf16 bf16x8 __attribute__((ext_vector_type(8)));
typedef __bf16 bf16x4 __attribute__((ext_vector_type(4)));
typedef float  f32x4  __attribute__((ext_vector_type(4)));

// ---------------------------------------------------------------------------
// Precompute (grid 129 x 64):
//  blocks 0..127: Mb = M = Wq^T Wk in bf16, pre-swizzled to MFMA B-fragment
//    layout: frag f = k_tile*16 + n_tile (k_tile<8, n_tile<16);
//    Mb[(f*64 + lane)*8 + j] = M[k_tile*32 + (lane>>4)*8 + j][n_tile*16 + (lane&15)]
//  block 128: rv[t] = sum_i bq[i] * Wk[i*256+t]  (fp32)
//  (bk and the h_src-only bias terms cancel in the softmax -> never computed)
// ---------------------------------------------------------------------------
__global__ __launch_bounds__(64) void precompute_kernel(
    const float* __restrict__ Wq, const float* __restrict__ Wk,
    const float* __restrict__ bq, __bf16* __restrict__ Mb, float* __restrict__ rv)
{
    const int f = blockIdx.x;
    const int lane = threadIdx.x;
    if (f < 128) {
        const int k_tile = f >> 4;
        const int n_t    = f & 15;
        const int d0 = k_tile * 32 + (lane >> 4) * 8;   // 8 consecutive d = K idx
        const int t  = n_t * 16 + (lane & 15);          // N idx
        float acc[8] = {0.f, 0.f, 0.f, 0.f, 0.f, 0.f, 0.f, 0.f};
        for (int i = 0; i < 256; ++i) {
            const float kv = Wk[i * 256 + t];
            const float4 q0 = *(const float4*)(Wq + i * 256 + d0);
            const float4 q1 = *(const float4*)(Wq + i * 256 + d0 + 4);
            acc[0] = fmaf(q0.x, kv, acc[0]);
            acc[1] = fmaf(q0.y, kv, acc[1]);
            acc[2] = fmaf(q0.z, kv, acc[2]);
            acc[3] = fmaf(q0.w, kv, acc[3]);
            acc[4] = fmaf(q1.x, kv, acc[4]);
            acc[5] = fmaf(q1.y, kv, acc[5]);
            acc[6] = fmaf(q1.z, kv, acc[6]);
            acc[7] = fmaf(q1.w, kv, acc[7]);
        }
        bf16x8 o;
        #pragma unroll
        for (int j = 0; j < 8; ++j) o[j] = (__bf16)acc[j];
        *(bf16x8*)(Mb + ((size_t)f * 64 + lane) * 8) = o;
    } else {
        #pragma unroll
        for (int q = 0; q < 4; ++q) {
            const int t = q * 64 + lane;
            float a0 = 0.f, a1 = 0.f;
            for (int i = 0; i < 256; i += 2) {
                a0 = fmaf(bq[i + 0], Wk[(i + 0) * 256 + t], a0);
                a1 = fmaf(bq[i + 1], Wk[(i + 1) * 256 + t], a1);
            }
            rv[t] = a0 + a1;
        }
    }
}

// ---------------------------------------------------------------------------
// Main fused kernel, MFMA version. One block (256 thr = 4 waves) per (b,l).
//  1) stage A = hs[b,:,l,:] (64x256) as bf16 in LDS
//  2) GEMM1 (per wave, N-strip of 64): T = A @ M + r, M frags streamed from
//     global (L2-hot, pre-swizzled), 128 MFMA/wave -> T bf16 to LDS
//  3) GEMM2 (per wave, M-strip of 16): S = T @ A^T, 32 MFMA/wave
//  4) S (x 1/sqrt(D)) -> LDS fp32 (overlaying dead hs buffer)
//  5) per-edge logits from S, group-of-16 softmax via shfl, write probs to ws
//     (or scattered ew_out directly if !USE_WS)
// ---------------------------------------------------------------------------
template <bool USE_WS>
__global__ __launch_bounds__(256) void edge_main(
    const float* __restrict__ hs, const int* __restrict__ eidx,
    const float* __restrict__ ew, const float* __restrict__ skipp,
    const __bf16* __restrict__ Mb, const float* __restrict__ rv,
    float* __restrict__ probs_or_out)
{
    __shared__ __bf16 hs_s[64 * STRB];
    __shared__ __bf16 T_s[64 * STRB];

    const int bl = blockIdx.x;          // 0..4095
    const int b  = bl >> 10;
    const int l  = bl & 1023;
    const int tid  = threadIdx.x;
    const int w    = tid >> 6;          // wave 0..3
    const int lane = tid & 63;
    const int l15  = lane & 15;
    const int quad = lane >> 4;

    // ---- stage hs tile (64 rows x 256 cols fp32 -> bf16), coalesced ----
    {
        const float* base = hs + ((size_t)b * 64 * 1024 + (size_t)l) * 256;
        const int c4 = (tid & 63) * 4;
        const int vo = tid >> 6;
        #pragma unroll
        for (int k = 0; k < 16; ++k) {
            const int v = k * 4 + vo;
            float4 val = *(const float4*)(base + (size_t)v * (1024 * 256) + c4);
            bf16x4 h;
            h[0] = (__bf16)val.x; h[1] = (__bf16)val.y;
            h[2] = (__bf16)val.z; h[3] = (__bf16)val.w;
            *(bf16x4*)(&hs_s[v * STRB + c4]) = h;
        }
    }
    __syncthreads();

    // ---- GEMM1: T[0:64][w*64 : w*64+64] = A @ M + r ----
    f32x4 acc[4][4];   // [m_tile][n_tile]
    #pragma unroll
    for (int nt = 0; nt < 4; ++nt) {
        const float rb = rv[w * 64 + nt * 16 + l15];
        #pragma unroll
        for (int mt = 0; mt < 4; ++mt) {
            acc[mt][nt][0] = rb; acc[mt][nt][1] = rb;
            acc[mt][nt][2] = rb; acc[mt][nt][3] = rb;
        }
    }
    #pragma unroll
    for (int kt = 0; kt < 8; ++kt) {
        bf16x8 afr[4];
        #pragma unroll
        for (int mt = 0; mt < 4; ++mt)
            afr[mt] = *(const bf16x8*)(&hs_s[(mt * 16 + l15) * STRB + kt * 32 + quad * 8]);
        bf16x8 bfr[4];
        #pragma unroll
        for (int nt = 0; nt < 4; ++nt)
            bfr[nt] = *(const bf16x8*)(Mb + ((size_t)(kt * 16 + w * 4 + nt) * 64 + lane) * 8);
        #pragma unroll
        for (int mt = 0; mt < 4; ++mt)
            #pragma unroll
            for (int nt = 0; nt < 4; ++nt)
                acc[mt][nt] = __builtin_amdgcn_mfma_f32_16x16x32_bf16(
                    afr[mt], bfr[nt], acc[mt][nt], 0, 0, 0);
    }

    // ---- T -> LDS bf16 (C-layout: row = mt*16 + quad*4 + r, col = lane&15) ----
    #pragma unroll
    for (int mt = 0; mt < 4; ++mt)
        #pragma unroll
        for (int nt = 0; nt < 4; ++nt)
            #pragma unroll
            for (int r = 0; r < 4; ++r) {
                const int row = mt * 16 + quad * 4 + r;
                const int col = w * 64 + nt * 16 + l15;
                T_s[row * STRB + col] = (__bf16)acc[mt][nt][r];
            }
    __syncthreads();

    // ---- GEMM2: S[w*16 : w*16+16][0:64] = T @ A^T ----
    f32x4 s_acc[4];
    #pragma unroll
    for (int nt = 0; nt < 4; ++nt) {
        s_acc[nt][0] = 0.f; s_acc[nt][1] = 0.f;
        s_acc[nt][2] = 0.f; s_acc[nt][3] = 0.f;
    }
    #pragma unroll
    for (int kt = 0; kt < 8; ++kt) {
        const bf16x8 afr = *(const bf16x8*)(&T_s[(w * 16 + l15) * STRB + kt * 32 + quad * 8]);
        #pragma unroll
        for (int nt = 0; nt < 4; ++nt) {
            const bf16x8 bfr = *(const bf16x8*)(&hs_s[(nt * 16 + l15) * STRB + kt * 32 + quad * 8]);
            s_acc[nt] = __builtin_amdgcn_mfma_f32_16x16x32_bf16(afr, bfr, s_acc[nt], 0, 0, 0);
        }
    }
    __syncthreads();   // all LDS reads done before we overlay S onto hs_s

    // ---- S (scaled by 1/sqrt(256)) -> LDS fp32, overlay on hs_s ----
    float* S_s = (float*)hs_s;      // 64 x 68 stride
    #pragma unroll
    for (int nt = 0; nt < 4; ++nt)
        #pragma unroll
        for (int r = 0; r < 4; ++r) {
            const int row = w * 16 + quad * 4 + r;
            const int col = nt * 16 + l15;
            S_s[row * 68 + col] = s_acc[nt][r] * 0.0625f;
        }
    __syncthreads();

    // ---- per-edge logits + group-of-16 softmax ----
    const int e0  = tid * 4;
    const int be0 = b * Ev + e0;
    int srcs[4], dsts[4];
    #pragma unroll
    for (int j = 0; j < 4; ++j) {
        srcs[j] = eidx[be0 + j];
        dsts[j] = eidx[BE + be0 + j];
    }
    float lg[4];
    #pragma unroll
    for (int j = 0; j < 4; ++j)
        lg[j] = S_s[srcs[j] * 68 + dsts[j]];

    float mx = fmaxf(fmaxf(lg[0], lg[1]), fmaxf(lg[2], lg[3]));
    mx = fmaxf(mx, __shfl_xor(mx, 1));
    mx = fmaxf(mx, __shfl_xor(mx, 2));
    float ex[4], sm = 0.f;
    #pragma unroll
    for (int j = 0; j < 4; ++j) { ex[j] = __expf(lg[j] - mx); sm += ex[j]; }
    sm += __shfl_xor(sm, 1);
    sm += __shfl_xor(sm, 2);
    const float inv = 1.0f / sm;

    if (USE_WS) {
        float4 o = make_float4(ex[0] * inv, ex[1] * inv, ex[2] * inv, ex[3] * inv);
        *(float4*)(probs_or_out + (size_t)bl * 1024 + e0) = o;
    } else {
        const float skip = skipp[0];
        const float om = 1.0f - skip;
        #pragma unroll
        for (int j = 0; j < 4; ++j) {
            float g = fmaf(skip, ew[be0 + j], om * (ex[j] * inv));
            probs_or_out[(size_t)(be0 + j) * Lv + l] = g;
        }
    }
}

// ---------------------------------------------------------------------------
// Output kernel: tiled transpose of probs (b,l,e) -> ew_out (be,l), plus ei
// broadcast. Block = (lt, et, b) transposes one 64x64 tile.
// ---------------------------------------------------------------------------
__global__ __launch_bounds__(256) void output_kernel(
    const float* __restrict__ probs, const int* __restrict__ eidx,
    const float* __restrict__ ew, const float* __restrict__ skipp,
    float* __restrict__ out)
{
    __shared__ float tile[64 * 68];
    const int lt = blockIdx.x;   // 0..15
    const int et = blockIdx.y;   // 0..15
    const int b  = blockIdx.z;   // 0..3
    const int t  = threadIdx.x;
    const int tr = t >> 4;       // 0..15
    const int tc = t & 15;       // 0..15

    #pragma unroll
    for (int q = 0; q < 4; ++q) {
        const int lloc = q * 16 + tr;
        float4 v = *(const float4*)(probs +
            ((size_t)(b * 1024 + lt * 64 + lloc)) * 1024 + et * 64 + tc * 4);
        *(float4*)(&tile[lloc * 68 + tc * 4]) = v;
    }
    __syncthreads();

    const float skip = skipp[0];
    const float om = 1.0f - skip;
    float* out_ei0 = out;
    float* out_ei1 = out + EI_PLANE;
    float* out_ew  = out + 2 * EI_PLANE;

    #pragma unroll
    for (int q = 0; q < 4; ++q) {
        const int eloc = q * 16 + tr;
        const int be = b * Ev + et * 64 + eloc;
        const float w  = ew[be];
        const float sv = (float)eidx[be];
        const float dv = (float)eidx[BE + be];
        const int lloc0 = tc * 4;
        float4 o;
        o.x = fmaf(skip, w, om * tile[(lloc0 + 0) * 68 + eloc]);
        o.y = fmaf(skip, w, om * tile[(lloc0 + 1) * 68 + eloc]);
        o.z = fmaf(skip, w, om * tile[(lloc0 + 2) * 68 + eloc]);
        o.w = fmaf(skip, w, om * tile[(lloc0 + 3) * 68 + eloc]);
        const size_t off = (size_t)be * Lv + lt * 64 + lloc0;
        *(float4*)(out_ew  + off) = o;
        *(float4*)(out_ei0 + off) = make_float4(sv, sv, sv, sv);
        *(float4*)(out_ei1 + off) = make_float4(dv, dv, dv, dv);
    }
}

// Fallback ei broadcast kernel (only used if ws too small for probs buffer)
__global__ __launch_bounds__(256) void ei_kernel(
    const int* __restrict__ eidx, float* __restrict__ out)
{
    const int blk = blockIdx.x;            // 0..8191  (c*4096 + j)
    const int c = blk >> 12;
    const int j = blk & 4095;
    const float v = (float)eidx[c * BE + j];
    float4 o = make_float4(v, v, v, v);
    *(float4*)(out + (size_t)blk * 1024 + threadIdx.x * 4) = o;
}

// ---------------------------------------------------------------------------
extern "C" void kernel_launch(void* const* d_in, const int* in_sizes, int n_in,
                              void* d_out, int out_size, void* d_ws, size_t ws_size,
                              hipStream_t stream)
{
    const float* hs   = (const float*)d_in[0];
    const int*   eidx = (const int*)d_in[1];
    const float* ew   = (const float*)d_in[2];
    const float* Wq   = (const float*)d_in[3];
    const float* bq   = (const float*)d_in[4];
    const float* Wk   = (const float*)d_in[5];
    // d_in[6] = bk: provably unused (cancels in softmax)
    const float* skip = (const float*)d_in[7];

    char* wsb = (char*)d_ws;
    __bf16* Mb   = (__bf16*)wsb;                       // 65536 bf16 = 128 KiB
    float*  rv   = (float*)(wsb + 131072);             // 256 fp32 = 1 KiB
    float*  probs = (float*)(wsb + 132096);            // 4M fp32 = 16 MiB
    const size_t need = 132096 + (size_t)Bv * Lv * Ev * sizeof(float);

    precompute_kernel<<<dim3(129), dim3(64), 0, stream>>>(Wq, Wk, bq, Mb, rv);

    if (ws_size >= need) {
        edge_main<true><<<dim3(Bv * Lv), dim3(256), 0, stream>>>(
            hs, eidx, ew, skip, Mb, rv, probs);
        output_kernel<<<dim3(16, 16, 4), dim3(256), 0, stream>>>(
            probs, eidx, ew, skip, (float*)d_out);
    } else {
        float* out_ew = (float*)d_out + 2 * EI_PLANE;
        edge_main<false><<<dim3(Bv * Lv), dim3(256), 0, stream>>>(
            hs, eidx, ew, skip, Mb, rv, out_ew);
        ei_kernel<<<dim3(2 * BE), dim3(256), 0, stream>>>(eidx, (float*)d_out);
    }
}

// Round 3
// 425.431 us; speedup vs baseline: 2.5803x; 1.0543x over previous
//
#include <hip/hip_runtime.h>
#include <cstdint>
#include <cstddef>

// Problem constants (B=4, V=64, E=1024, L=1024, D=256, DEG=16)
constexpr int Bv = 4;
constexpr int Vv = 64;
constexpr int Ev = 1024;      // edges per batch
constexpr int Lv = 1024;
constexpr int BE = Bv * Ev;   // 4096
constexpr size_t EI_PLANE = (size_t)BE * Lv;  // 4,194,304 elements per ei plane

// bf16 LDS row stride for hs tile: 256 + 8 pad -> 528 B rows (16B aligned;
// fragment b128 reads land 2-way on banks = free)
constexpr int STRB = 264;
// T chunk (64 x 128 bf16) stride: 128 + 8 pad -> 272 B rows
constexpr int TSTR = 136;

typedef __bf16 bf16x8 __attribute__((ext_vector_type(8)));
typedef __bf16 bf16x4 __attribute__((ext_vector_type(4)));
typedef float  f32x4  __attribute__((ext_vector_type(4)));

// ---------------------------------------------------------------------------
// Precompute v2 (grid 257 x 256 threads):
//  blocks 0..255: tile (i = blk>>4, j = blk&15) of M' = (Wq^T Wk) / 16,
//    bf16, written pre-swizzled to MFMA B-fragment layout:
//      for element (d, t):  f = (d>>5)*16 + (t>>4);
//                           lane = ((d>>3)&3)*16 + (t&15); jj = d&7;
//      Mb[(f*64 + lane)*8 + jj] = M'[d][t]
//  block 256: rv[t] = (sum_i bq[i] * Wk[i*256+t]) / 16  (fp32)
//  (bk and the h_src-only bias terms cancel in the softmax -> never computed;
//   the 1/sqrt(D)=1/16 logit scale is folded in here.)
// ---------------------------------------------------------------------------
__global__ __launch_bounds__(256) void precompute_kernel(
    const float* __restrict__ Wq, const float* __restrict__ Wk,
    const float* __restrict__ bq, __bf16* __restrict__ Mb, float* __restrict__ rv)
{
    const int blk = blockIdx.x;
    const int tid = threadIdx.x;
    if (blk < 256) {
        __shared__ float qs[256 * 17];
        __shared__ float ks[256 * 17];
        const int i16 = (blk >> 4) * 16;   // d-tile base
        const int j16 = (blk & 15) * 16;   // t-tile base
        const int c  = tid & 15;
        const int r0 = tid >> 4;
        #pragma unroll
        for (int it = 0; it < 16; ++it) {
            const int r = it * 16 + r0;
            qs[r * 17 + c] = Wq[r * 256 + i16 + c];
            ks[r * 17 + c] = Wk[r * 256 + j16 + c];
        }
        __syncthreads();
        const int dd = tid >> 4;   // 0..15 local d
        const int tt = tid & 15;   // 0..15 local t
        float a0 = 0.f, a1 = 0.f, a2 = 0.f, a3 = 0.f;
        for (int r = 0; r < 256; r += 4) {
            a0 = fmaf(qs[(r + 0) * 17 + dd], ks[(r + 0) * 17 + tt], a0);
            a1 = fmaf(qs[(r + 1) * 17 + dd], ks[(r + 1) * 17 + tt], a1);
            a2 = fmaf(qs[(r + 2) * 17 + dd], ks[(r + 2) * 17 + tt], a2);
            a3 = fmaf(qs[(r + 3) * 17 + dd], ks[(r + 3) * 17 + tt], a3);
        }
        const float m = ((a0 + a1) + (a2 + a3)) * 0.0625f;
        const int d = i16 + dd, t = j16 + tt;
        const int f    = (d >> 5) * 16 + (t >> 4);
        const int lane = ((d >> 3) & 3) * 16 + (t & 15);
        const int jj   = d & 7;
        Mb[((size_t)f * 64 + lane) * 8 + jj] = (__bf16)m;
    } else {
        __shared__ float bqs[256];
        bqs[tid] = bq[tid];
        __syncthreads();
        float a0 = 0.f, a1 = 0.f;
        for (int i = 0; i < 256; i += 2) {
            a0 = fmaf(bqs[i + 0], Wk[(i + 0) * 256 + tid], a0);
            a1 = fmaf(bqs[i + 1], Wk[(i + 1) * 256 + tid], a1);
        }
        rv[tid] = (a0 + a1) * 0.0625f;
    }
}

// ---------------------------------------------------------------------------
// Main fused kernel, MFMA + chunked-T version. One block (4 waves) per (b,l).
// LDS = hs (33.8 KB) + T-chunk/S (17.4 KB) = 51.2 KB -> 3 blocks/CU.
//  1) stage A = hs[b,:,l,:] (64x256) as bf16 in LDS
//  2) for chunk c in {0,1} (T columns c*128 .. c*128+128):
//       GEMM1: T_chunk = A @ M'[:, cols] + r' (per wave: 4m x 2n x 8k = 64 MFMA)
//       GEMM2 partial: S += T_chunk @ (A[:, cols])^T (per wave: 4n x 4k = 16 MFMA)
//  3) S (already scaled, fp32) -> overlay on T buffer
//  4) per-edge logits from S, group-of-16 softmax via shfl, write probs to ws
//     (or scattered ew_out directly if !USE_WS)
// ---------------------------------------------------------------------------
template <bool USE_WS>
__global__ __launch_bounds__(256) void edge_main(
    const float* __restrict__ hs, const int* __restrict__ eidx,
    const float* __restrict__ ew, const float* __restrict__ skipp,
    const __bf16* __restrict__ Mb, const float* __restrict__ rv,
    float* __restrict__ probs_or_out)
{
    __shared__ __bf16 hs_s[64 * STRB];          // 33.8 KB
    __shared__ float  Tbuf[64 * TSTR / 2];      // 17.4 KB (bf16 T chunk / fp32 S)
    __bf16* T16 = (__bf16*)Tbuf;
    float*  S_s = Tbuf;                          // 64 x 68 fp32 view

    const int bl = blockIdx.x;          // 0..4095
    const int b  = bl >> 10;
    const int l  = bl & 1023;
    const int tid  = threadIdx.x;
    const int w    = tid >> 6;          // wave 0..3
    const int lane = tid & 63;
    const int l15  = lane & 15;
    const int quad = lane >> 4;

    // ---- stage hs tile (64 rows x 256 cols fp32 -> bf16), coalesced ----
    {
        const float* base = hs + ((size_t)b * 64 * 1024 + (size_t)l) * 256;
        const int c4 = (tid & 63) * 4;
        const int vo = tid >> 6;
        #pragma unroll
        for (int k = 0; k < 16; ++k) {
            const int v = k * 4 + vo;
            float4 val = *(const float4*)(base + (size_t)v * (1024 * 256) + c4);
            bf16x4 h;
            h[0] = (__bf16)val.x; h[1] = (__bf16)val.y;
            h[2] = (__bf16)val.z; h[3] = (__bf16)val.w;
            *(bf16x4*)(&hs_s[v * STRB + c4]) = h;
        }
    }
    __syncthreads();

    f32x4 s_acc[4];                      // S rows w*16.., all 64 dst cols
    #pragma unroll
    for (int nt = 0; nt < 4; ++nt) {
        s_acc[nt][0] = 0.f; s_acc[nt][1] = 0.f;
        s_acc[nt][2] = 0.f; s_acc[nt][3] = 0.f;
    }

    #pragma unroll
    for (int cch = 0; cch < 2; ++cch) {
        // ---- GEMM1: T[:, local 0..128] = A @ M' + r' (wave n-strip of 32) ----
        f32x4 acc[4][2];   // [m_tile][n_tile]
        #pragma unroll
        for (int nt = 0; nt < 2; ++nt) {
            const float rb = rv[cch * 128 + w * 32 + nt * 16 + l15];
            #pragma unroll
            for (int mt = 0; mt < 4; ++mt) {
                acc[mt][nt][0] = rb; acc[mt][nt][1] = rb;
                acc[mt][nt][2] = rb; acc[mt][nt][3] = rb;
            }
        }
        #pragma unroll
        for (int kt = 0; kt < 8; ++kt) {
            bf16x8 afr[4];
            #pragma unroll
            for (int mt = 0; mt < 4; ++mt)
                afr[mt] = *(const bf16x8*)(&hs_s[(mt * 16 + l15) * STRB + kt * 32 + quad * 8]);
            bf16x8 bfr[2];
            #pragma unroll
            for (int nt = 0; nt < 2; ++nt)
                bfr[nt] = *(const bf16x8*)(Mb +
                    ((size_t)(kt * 16 + cch * 8 + w * 2 + nt) * 64 + lane) * 8);
            #pragma unroll
            for (int mt = 0; mt < 4; ++mt)
                #pragma unroll
                for (int nt = 0; nt < 2; ++nt)
                    acc[mt][nt] = __builtin_amdgcn_mfma_f32_16x16x32_bf16(
                        afr[mt], bfr[nt], acc[mt][nt], 0, 0, 0);
        }
        // T chunk -> LDS bf16 (C layout: row = mt*16+quad*4+r, col local)
        #pragma unroll
        for (int mt = 0; mt < 4; ++mt)
            #pragma unroll
            for (int nt = 0; nt < 2; ++nt)
                #pragma unroll
                for (int r = 0; r < 4; ++r)
                    T16[(mt * 16 + quad * 4 + r) * TSTR + w * 32 + nt * 16 + l15] =
                        (__bf16)acc[mt][nt][r];
        __syncthreads();

        // ---- GEMM2 partial: S += T_chunk @ (A[:, chunk cols])^T ----
        #pragma unroll
        for (int kt2 = 0; kt2 < 4; ++kt2) {
            const bf16x8 afr = *(const bf16x8*)(&T16[(w * 16 + l15) * TSTR + kt2 * 32 + quad * 8]);
            #pragma unroll
            for (int nt = 0; nt < 4; ++nt) {
                const bf16x8 bfr = *(const bf16x8*)(
                    &hs_s[(nt * 16 + l15) * STRB + cch * 128 + kt2 * 32 + quad * 8]);
                s_acc[nt] = __builtin_amdgcn_mfma_f32_16x16x32_bf16(afr, bfr, s_acc[nt], 0, 0, 0);
            }
        }
        __syncthreads();   // T reads done before next chunk overwrites / S overlay
    }

    // ---- S (already scaled) -> LDS fp32, overlay on T buffer ----
    #pragma unroll
    for (int nt = 0; nt < 4; ++nt)
        #pragma unroll
        for (int r = 0; r < 4; ++r)
            S_s[(w * 16 + quad * 4 + r) * 68 + nt * 16 + l15] = s_acc[nt][r];
    __syncthreads();

    // ---- per-edge logits + group-of-16 softmax ----
    const int e0  = tid * 4;
    const int be0 = b * Ev + e0;
    int srcs[4], dsts[4];
    #pragma unroll
    for (int j = 0; j < 4; ++j) {
        srcs[j] = eidx[be0 + j];
        dsts[j] = eidx[BE + be0 + j];
    }
    float lg[4];
    #pragma unroll
    for (int j = 0; j < 4; ++j)
        lg[j] = S_s[srcs[j] * 68 + dsts[j]];

    float mx = fmaxf(fmaxf(lg[0], lg[1]), fmaxf(lg[2], lg[3]));
    mx = fmaxf(mx, __shfl_xor(mx, 1));
    mx = fmaxf(mx, __shfl_xor(mx, 2));
    float ex[4], sm = 0.f;
    #pragma unroll
    for (int j = 0; j < 4; ++j) { ex[j] = __expf(lg[j] - mx); sm += ex[j]; }
    sm += __shfl_xor(sm, 1);
    sm += __shfl_xor(sm, 2);
    const float inv = 1.0f / sm;

    if (USE_WS) {
        float4 o = make_float4(ex[0] * inv, ex[1] * inv, ex[2] * inv, ex[3] * inv);
        *(float4*)(probs_or_out + (size_t)bl * 1024 + e0) = o;
    } else {
        const float skip = skipp[0];
        const float om = 1.0f - skip;
        #pragma unroll
        for (int j = 0; j < 4; ++j) {
            float g = fmaf(skip, ew[be0 + j], om * (ex[j] * inv));
            probs_or_out[(size_t)(be0 + j) * Lv + l] = g;
        }
    }
}

// ---------------------------------------------------------------------------
// Output kernel: tiled transpose of probs (b,l,e) -> ew_out (be,l), plus ei
// broadcast. Block = (lt, et, b) transposes one 64x64 tile.
// ---------------------------------------------------------------------------
__global__ __launch_bounds__(256) void output_kernel(
    const float* __restrict__ probs, const int* __restrict__ eidx,
    const float* __restrict__ ew, const float* __restrict__ skipp,
    float* __restrict__ out)
{
    __shared__ float tile[64 * 68];
    const int lt = blockIdx.x;   // 0..15
    const int et = blockIdx.y;   // 0..15
    const int b  = blockIdx.z;   // 0..3
    const int t  = threadIdx.x;
    const int tr = t >> 4;       // 0..15
    const int tc = t & 15;       // 0..15

    #pragma unroll
    for (int q = 0; q < 4; ++q) {
        const int lloc = q * 16 + tr;
        float4 v = *(const float4*)(probs +
            ((size_t)(b * 1024 + lt * 64 + lloc)) * 1024 + et * 64 + tc * 4);
        *(float4*)(&tile[lloc * 68 + tc * 4]) = v;
    }
    __syncthreads();

    const float skip = skipp[0];
    const float om = 1.0f - skip;
    float* out_ei0 = out;
    float* out_ei1 = out + EI_PLANE;
    float* out_ew  = out + 2 * EI_PLANE;

    #pragma unroll
    for (int q = 0; q < 4; ++q) {
        const int eloc = q * 16 + tr;
        const int be = b * Ev + et * 64 + eloc;
        const float w  = ew[be];
        const float sv = (float)eidx[be];
        const float dv = (float)eidx[BE + be];
        const int lloc0 = tc * 4;
        float4 o;
        o.x = fmaf(skip, w, om * tile[(lloc0 + 0) * 68 + eloc]);
        o.y = fmaf(skip, w, om * tile[(lloc0 + 1) * 68 + eloc]);
        o.z = fmaf(skip, w, om * tile[(lloc0 + 2) * 68 + eloc]);
        o.w = fmaf(skip, w, om * tile[(lloc0 + 3) * 68 + eloc]);
        const size_t off = (size_t)be * Lv + lt * 64 + lloc0;
        *(float4*)(out_ew  + off) = o;
        *(float4*)(out_ei0 + off) = make_float4(sv, sv, sv, sv);
        *(float4*)(out_ei1 + off) = make_float4(dv, dv, dv, dv);
    }
}

// Fallback ei broadcast kernel (only used if ws too small for probs buffer)
__global__ __launch_bounds__(256) void ei_kernel(
    const int* __restrict__ eidx, float* __restrict__ out)
{
    const int blk = blockIdx.x;            // 0..8191  (c*4096 + j)
    const int c = blk >> 12;
    const int j = blk & 4095;
    const float v = (float)eidx[c * BE + j];
    float4 o = make_float4(v, v, v, v);
    *(float4*)(out + (size_t)blk * 1024 + threadIdx.x * 4) = o;
}

// ---------------------------------------------------------------------------
extern "C" void kernel_launch(void* const* d_in, const int* in_sizes, int n_in,
                              void* d_out, int out_size, void* d_ws, size_t ws_size,
                              hipStream_t stream)
{
    const float* hs   = (const float*)d_in[0];
    const int*   eidx = (const int*)d_in[1];
    const float* ew   = (const float*)d_in[2];
    const float* Wq   = (const float*)d_in[3];
    const float* bq   = (const float*)d_in[4];
    const float* Wk   = (const float*)d_in[5];
    // d_in[6] = bk: provably unused (cancels in softmax)
    const float* skip = (const float*)d_in[7];

    char* wsb = (char*)d_ws;
    __bf16* Mb   = (__bf16*)wsb;                       // 65536 bf16 = 128 KiB
    float*  rv   = (float*)(wsb + 131072);             // 256 fp32 = 1 KiB
    float*  probs = (float*)(wsb + 132096);            // 4M fp32 = 16 MiB
    const size_t need = 132096 + (size_t)Bv * Lv * Ev * sizeof(float);

    precompute_kernel<<<dim3(257), dim3(256), 0, stream>>>(Wq, Wk, bq, Mb, rv);

    if (ws_size >= need) {
        edge_main<true><<<dim3(Bv * Lv), dim3(256), 0, stream>>>(
            hs, eidx, ew, skip, Mb, rv, probs);
        output_kernel<<<dim3(16, 16, 4), dim3(256), 0, stream>>>(
            probs, eidx, ew, skip, (float*)d_out);
    } else {
        float* out_ew = (float*)d_out + 2 * EI_PLANE;
        edge_main<false><<<dim3(Bv * Lv), dim3(256), 0, stream>>>(
            hs, eidx, ew, skip, Mb, rv, out_ew);
        ei_kernel<<<dim3(2 * BE), dim3(256), 0, stream>>>(eidx, (float*)d_out);
    }
}